// Round 17
// baseline (138.673 us; speedup 1.0000x reference)
//
#include <hip/hip_runtime.h>
#include <hip/hip_bf16.h>

// Output layout (ALL float32):
//   out[0        .. 8388608)  quantized_st  [4,64,32,32,32]
//   out[8388608  .. 8519680)  embed_idx as float  [4,32,32,32]
//   out[8519680]              latent_loss scalar
#define HWD      32768
#define NC       64
#define NE       512
#define OUT_IDX  8388608
#define OUT_LOSS 8519680

// ws layout (bytes):
//   [0..4)   loss accumulator (fallback only)   [4..8) counter (unused)
//   [64..2112)   wsq[512]
//   [2112..3136) 256 loss partial slots (R14)
//   [4096..200704) wp 3-plane bf16 codebook (R17 16-code-tile swizzle)
#define WS_WSQ_F   16
#define WS_SLOT_F  528
#define WS_WP_B    4096
#define WS_NEEDED  200704

typedef __attribute__((ext_vector_type(8))) short bf16x8;
typedef __attribute__((ext_vector_type(4))) float f32x4;

__device__ inline unsigned short bf16_rne(float v) {
    unsigned u = __builtin_bit_cast(unsigned, v);
    return (unsigned short)((u + 0x7FFFu + ((u >> 16) & 1u)) >> 16);
}
__device__ inline float bf16_f(unsigned short s) {
    return __builtin_bit_cast(float, (unsigned)s << 16);
}
__device__ inline void split3(float v, unsigned short& h, unsigned short& m,
                              unsigned short& l) {
    h = bf16_rne(v);
    float r1 = v - bf16_f(h);
    m = bf16_rne(r1);
    float r2 = r1 - bf16_f(m);
    l = bf16_rne(r2);
}

// ---------------- prep: zero accumulators, wsq, split+swizzle codebook ----
__global__ __launch_bounds__(256) void vq_prep(
    const float* __restrict__ w, float* __restrict__ ws)
{
    const int gtid = blockIdx.x * 256 + threadIdx.x;   // 0..12287
    if (gtid == 0) { ws[0] = 0.f; ((unsigned*)ws)[1] = 0u; }
    if (gtid < 256) ws[WS_SLOT_F + gtid] = 0.f;        // R14 loss slots
    if (gtid < NE) {
        const float4* row = (const float4*)(w + (size_t)gtid * NC);
        float s0 = 0.f, s1 = 0.f, s2 = 0.f, s3 = 0.f;
#pragma unroll
        for (int k = 0; k < 16; ++k) {
            float4 v = row[k];
            s0 = fmaf(v.x, v.x, s0); s1 = fmaf(v.y, v.y, s1);
            s2 = fmaf(v.z, v.z, s2); s3 = fmaf(v.w, v.w, s3);
        }
        ws[WS_WSQ_F + gtid] = (s0 + s1) + (s2 + s3);
    }
    const int lane_s = gtid & 63;
    int t = gtid >> 6;            // 0..191
    const int plane = t % 3; t /= 3;
    const int kc = t & 1;
    const int ct = t >> 1;
    const int code = ct * 16 + (lane_s & 15);
    const int kb   = kc * 32 + (lane_s >> 4) * 8;
    const float* src = w + (size_t)code * NC + kb;
    unsigned short o[8];
#pragma unroll
    for (int j = 0; j < 8; ++j) {
        unsigned short h, m, l;
        split3(src[j], h, m, l);
        o[j] = (plane == 0) ? h : (plane == 1) ? m : l;
    }
    unsigned short* dst = (unsigned short*)((char*)ws + WS_WP_B) + (size_t)gtid * 8;
#pragma unroll
    for (int j = 0; j < 8; ++j) dst[j] = o[j];
}

// ---- helpers -------------------------------------------------------------
__device__ __forceinline__ void loadB(const bf16x8* __restrict__ wp,
                                      const float* __restrict__ wsqp,
                                      const int ct, const int lane,
                                      const int lanelo,
                                      bf16x8 (&B)[2][3], float& wsq)
{
#pragma unroll
    for (int kc = 0; kc < 2; ++kc)
#pragma unroll
        for (int p = 0; p < 3; ++p)
            B[kc][p] = wp[(size_t)((ct * 2 + kc) * 3 + p) * 64 + lane];
    wsq = wsqp[ct * 16 + lanelo];
}

// NOTE R11 (verified): xsq dropped — uniform over codes, argmin unchanged.
// 2 interleaved pt-chains (dep distance 2); per-acc product order identical
// to R7..R21 — bit-identical numerics per position.
__device__ __forceinline__ void tileUpd2(const bf16x8 (&A)[2][2][3],
                                         const bf16x8 (&B)[2][3],
                                         const float wsq, const int ct,
                                         const int lanelo,
                                         float (&best)[2][4], int (&bidx)[2][4])
{
    constexpr int AP[6] = {2, 1, 0, 1, 0, 0};
    constexpr int BP[6] = {0, 1, 2, 0, 1, 0};
    f32x4 acc[2];
#pragma unroll
    for (int pt = 0; pt < 2; ++pt) acc[pt] = (f32x4){0.f, 0.f, 0.f, 0.f};
#pragma unroll
    for (int s = 0; s < 12; ++s) {
        const int kc = s & 1, ap = AP[s >> 1], bp = BP[s >> 1];
#pragma unroll
        for (int pt = 0; pt < 2; ++pt)
            acc[pt] = __builtin_amdgcn_mfma_f32_16x16x32_bf16(
                A[pt][kc][ap], B[kc][bp], acc[pt], 0, 0, 0);
    }
#pragma unroll
    for (int pt = 0; pt < 2; ++pt)
#pragma unroll
        for (int r = 0; r < 4; ++r) {
            const float d = fmaf(-2.f, acc[pt][r], wsq);
            if (d < best[pt][r]) { best[pt][r] = d; bidx[pt][r] = ct * 16 + lanelo; }
        }
}

// ---------------- kernel A: argmin (R24: grid-doubled R17) ----------------
// R23 diagnosis: R17's VGPR=112 already PERMITS 4 waves/SIMD — occupancy
// was grid-limited (512 blocks = 2/CU), not register-limited. R22 broke
// this test by shrinking the block (128-thr -> 64-reg clamp + spill). R24
// runs it on the proven chassis: 256-thr blocks, (256,2), pt=2 (32
// pos/wave, demand ~88 <= 128 cap — spill excluded by construction), grid
// 1024 -> 4 blocks/CU = 4 waves/SIMD. Cost: 2x codebook L2 traffic
// (800 MB ~ 20 TB/s < 34.5). Numerics bit-identical. Pre-committed read:
// dur ~52 unchanged at doubled occupancy => issue-bound plateau, stop.
__global__ __launch_bounds__(256, 2) void vq_argmin(
    const float* __restrict__ x, float* __restrict__ ws,
    float* __restrict__ out)
{
    __shared__ int idx_sh[128];

    const int tid    = threadIdx.x;
    const int wv     = tid >> 6;
    const int lane   = tid & 63;
    const int lanelo = lane & 15;
    const int quad   = lane >> 4;
    const int posB   = blockIdx.x * 128;
    const int b      = posB >> 15;
    const int hwdB   = posB & (HWD - 1);
    const size_t xoff = (size_t)b * NC * HWD + hwdB;
    const int wpos   = wv * 32;                  // 32 positions per wave

    const bf16x8* wp   = (const bf16x8*)((const char*)ws + WS_WP_B);
    const float*  wsqp = ws + WS_WSQ_F;

    // issue tile-0 B load NOW so L2 latency rides under the x prologue
    bf16x8 B0[2][3], B1[2][3];
    float  w0, w1;
    loadB(wp, wsqp, 0, lane, lanelo, B0, w0);

    // ---- phase 1: A-fragments, 2 position-subtiles (3 exact bf16 planes) -
    bf16x8 A[2][2][3];
#pragma unroll
    for (int pt = 0; pt < 2; ++pt) {
#pragma unroll
        for (int kc = 0; kc < 2; ++kc) {
            bf16x8 fh, fm, fl;
#pragma unroll
            for (int j = 0; j < 8; ++j) {
                const int k = kc * 32 + quad * 8 + j;
                const float v = x[xoff + (size_t)k * HWD + wpos + pt * 16 + lanelo];
                unsigned short h, m, l;
                split3(v, h, m, l);
                fh[j] = (short)h; fm[j] = (short)m; fl[j] = (short)l;
            }
            A[pt][kc][0] = fh; A[pt][kc][1] = fm; A[pt][kc][2] = fl;
        }
    }

    float best[2][4];
    int   bidx[2][4];
#pragma unroll
    for (int pt = 0; pt < 2; ++pt)
#pragma unroll
        for (int r = 0; r < 4; ++r) { best[pt][r] = 3.402823466e38f; bidx[pt][r] = 0; }

    // ---- phase 2: 32 tiles, ping-pong reg prefetch, NO barriers ----------
#pragma unroll 1
    for (int r = 0; r < 16; ++r) {
        const int ce = r * 2;
        loadB(wp, wsqp, ce + 1, lane, lanelo, B1, w1);          // prefetch odd
        tileUpd2(A, B0, w0, ce, lanelo, best, bidx);            // compute even
        loadB(wp, wsqp, (ce + 2) & 31, lane, lanelo, B0, w0);   // prefetch next
        tileUpd2(A, B1, w1, ce + 1, lanelo, best, bidx);        // compute odd
    }

    // ---- phase 3: argmin across 16 code-columns (np first-index ties) ----
#pragma unroll
    for (int pt = 0; pt < 2; ++pt)
#pragma unroll
        for (int r = 0; r < 4; ++r) {
            float d = best[pt][r]; int i = bidx[pt][r];
#pragma unroll
            for (int mlane = 1; mlane <= 8; mlane <<= 1) {
                const float d2 = __shfl_xor(d, mlane);
                const int   i2 = __shfl_xor(i, mlane);
                if (d2 < d || (d2 == d && i2 < i)) { d = d2; i = i2; }
            }
            if (lanelo == 0)
                idx_sh[wpos + pt * 16 + quad * 4 + r] = i;
        }
    __syncthreads();

    if (tid < 128) out[OUT_IDX + posB + tid] = (float)idx_sh[tid];
}

// ---------------- kernel B: streaming epilogue (R15 float4, verified) -----
__global__ __launch_bounds__(256, 8) void vq_epilogue(
    const float* __restrict__ x, const float* __restrict__ w,
    float* __restrict__ ws, float* __restrict__ out)
{
    __shared__ float q_t[64 * 68];     // 17.4 KB, [channel][pos], pad 68
    __shared__ int   idx_sh[64];
    __shared__ float wred[4];

    const int tid  = threadIdx.x;
    const int posB = blockIdx.x * 64;
    const int b    = posB >> 15;
    const int hwdB = posB & (HWD - 1);
    const size_t xoff = (size_t)b * NC * HWD + hwdB;

    if (tid < 64) idx_sh[tid] = (int)out[OUT_IDX + posB + tid];
    __syncthreads();

#pragma unroll
    for (int it = 0; it < 16; ++it) {
        const int e = it * 256 + tid;
        const int r = e >> 6, c = e & 63;
        q_t[c * 68 + r] = w[(size_t)idx_sh[r] * NC + c];
    }
    __syncthreads();

    float lsum = 0.f;
#pragma unroll
    for (int it = 0; it < 4; ++it) {
        const int s  = it * 256 + tid;
        const int c  = s >> 4;             // 0..63
        const int p0 = (s & 15) * 4;       // 0,4,..,60
        const size_t off = xoff + (size_t)c * HWD + p0;
        const float4 xv = *(const float4*)(x + off);
        const float4 qv = *(const float4*)(q_t + c * 68 + p0);
        const float dx = qv.x - xv.x, dy = qv.y - xv.y;
        const float dz = qv.z - xv.z, dw = qv.w - xv.w;
        lsum = fmaf(dx, dx, lsum); lsum = fmaf(dy, dy, lsum);
        lsum = fmaf(dz, dz, lsum); lsum = fmaf(dw, dw, lsum);
        float4 ov;
        ov.x = dx + xv.x; ov.y = dy + xv.y;
        ov.z = dz + xv.z; ov.w = dw + xv.w;
        *(float4*)(out + off) = ov;
    }

#pragma unroll
    for (int off = 32; off >= 1; off >>= 1) lsum += __shfl_down(lsum, off);
    if ((tid & 63) == 0) wred[tid >> 6] = lsum;
    __syncthreads();
    if (tid == 0)
        atomicAdd(ws + WS_SLOT_F + (blockIdx.x & 255),
                  (wred[0] + wred[1]) + (wred[2] + wred[3]));
}

// ---------------- kernel C: reduce the 256 loss slots ---------------------
__global__ __launch_bounds__(64) void vq_loss_fin(
    const float* __restrict__ ws, float* __restrict__ out)
{
    const int lane = threadIdx.x;
    float s = (ws[WS_SLOT_F + lane]       + ws[WS_SLOT_F + lane + 64]) +
              (ws[WS_SLOT_F + lane + 128] + ws[WS_SLOT_F + lane + 192]);
#pragma unroll
    for (int off = 32; off >= 1; off >>= 1) s += __shfl_down(s, off);
    if (lane == 0) out[OUT_LOSS] = 0.25f * s / 8388608.0f;
}

// ---------------- fallback (R4 structure, known-passing) ------------------
__global__ __launch_bounds__(256, 2) void vq_fused_fb(
    const float* __restrict__ x, const float* __restrict__ w,
    float* __restrict__ out, float* __restrict__ loss_acc)
{
    __shared__ float lw[256 * NC];
    __shared__ float wsq[256];
    __shared__ float wred[4];
    const int tid = threadIdx.x;
    const int n0  = blockIdx.x * 512;
    const int b   = n0 >> 15;
    const int hwd = (n0 & (HWD - 1)) + tid;
    const float* xp = x + (size_t)b * NC * HWD + hwd;
    float xr0[NC], xr1[NC];
#pragma unroll
    for (int c = 0; c < NC; ++c) { xr0[c] = xp[(size_t)c * HWD]; xr1[c] = xp[(size_t)c * HWD + 256]; }
    float xsq0 = 0.f, xsq1 = 0.f;
#pragma unroll
    for (int c = 0; c < NC; ++c) { xsq0 = fmaf(xr0[c], xr0[c], xsq0); xsq1 = fmaf(xr1[c], xr1[c], xsq1); }
    float best0 = 3.402823466e38f, best1 = 3.402823466e38f;
    int bi0 = 0, bi1 = 0;
    for (int pass = 0; pass < 2; ++pass) {
        if (pass) __syncthreads();
        const float4* wt = (const float4*)(w + pass * 256 * NC);
        float4* l4 = (float4*)lw;
#pragma unroll
        for (int k = 0; k < 16; ++k) l4[tid + k * 256] = wt[tid + k * 256];
        {
            const float4* row = wt + tid * 16;
            float s0 = 0.f, s1 = 0.f, s2 = 0.f, s3 = 0.f;
#pragma unroll
            for (int k = 0; k < 16; ++k) {
                float4 v = row[k];
                s0 = fmaf(v.x, v.x, s0); s1 = fmaf(v.y, v.y, s1);
                s2 = fmaf(v.z, v.z, s2); s3 = fmaf(v.w, v.w, s3);
            }
            wsq[tid] = (s0 + s1) + (s2 + s3);
        }
        __syncthreads();
#pragma unroll 2
        for (int e = 0; e < 256; ++e) {
            const float4* row = (const float4*)(lw + e * NC);
            float a0 = 0.f, a1 = 0.f, c0 = 0.f, c1 = 0.f;
#pragma unroll
            for (int k = 0; k < 16; ++k) {
                float4 v = row[k];
                a0 = fmaf(xr0[4 * k + 0], v.x, a0); a1 = fmaf(xr0[4 * k + 1], v.y, a1);
                a0 = fmaf(xr0[4 * k + 2], v.z, a0); a1 = fmaf(xr0[4 * k + 3], v.w, a1);
                c0 = fmaf(xr1[4 * k + 0], v.x, c0); c1 = fmaf(xr1[4 * k + 1], v.y, c1);
                c0 = fmaf(xr1[4 * k + 2], v.z, c0); c1 = fmaf(xr1[4 * k + 3], v.w, c1);
            }
            const float d0 = (xsq0 - 2.f * (a0 + a1)) + wsq[e];
            const float d1 = (xsq1 - 2.f * (c0 + c1)) + wsq[e];
            const int ge = pass * 256 + e;
            if (d0 < best0) { best0 = d0; bi0 = ge; }
            if (d1 < best1) { best1 = d1; bi1 = ge; }
        }
    }
    float* o0 = out + (size_t)b * NC * HWD + hwd;
    float lsum = 0.f;
    const float4* r0 = (const float4*)(w + bi0 * NC);
    const float4* r1 = (const float4*)(w + bi1 * NC);
#pragma unroll
    for (int k = 0; k < 16; ++k) {
        float4 q0 = r0[k], q1 = r1[k];
        float qv0[4] = { q0.x, q0.y, q0.z, q0.w };
        float qv1[4] = { q1.x, q1.y, q1.z, q1.w };
#pragma unroll
        for (int j = 0; j < 4; ++j) {
            const int c = 4 * k + j;
            const float dv0 = qv0[j] - xr0[c];
            const float dv1 = qv1[j] - xr1[c];
            lsum = fmaf(dv0, dv0, lsum); lsum = fmaf(dv1, dv1, lsum);
            o0[(size_t)c * HWD] = dv0 + xr0[c];
            o0[(size_t)c * HWD + 256] = dv1 + xr1[c];
        }
    }
    const int n = b * HWD + hwd;
    out[OUT_IDX + n] = (float)bi0;
    out[OUT_IDX + n + 256] = (float)bi1;
#pragma unroll
    for (int off = 32; off >= 1; off >>= 1) lsum += __shfl_down(lsum, off);
    if ((tid & 63) == 0) wred[tid >> 6] = lsum;
    __syncthreads();
    if (tid == 0) atomicAdd(loss_acc, (wred[0] + wred[1]) + (wred[2] + wred[3]));
}

__global__ void vq_loss_fin_fb(const float* __restrict__ acc, float* __restrict__ out)
{
    out[OUT_LOSS] = 0.25f * acc[0] / 8388608.0f;
}

extern "C" void kernel_launch(void* const* d_in, const int* in_sizes, int n_in,
                              void* d_out, int out_size, void* d_ws, size_t ws_size,
                              hipStream_t stream)
{
    const float* x = (const float*)d_in[0];
    const float* w = (const float*)d_in[1];
    float* out = (float*)d_out;
    float* ws  = (float*)d_ws;

    if (ws_size >= WS_NEEDED) {
        vq_prep<<<48, 256, 0, stream>>>(w, ws);
        vq_argmin<<<1024, 256, 0, stream>>>(x, ws, out);
        vq_epilogue<<<2048, 256, 0, stream>>>(x, w, ws, out);
        vq_loss_fin<<<1, 64, 0, stream>>>(ws, out);
    } else {
        hipMemsetAsync(d_ws, 0, sizeof(float), stream);
        vq_fused_fb<<<256, 256, 0, stream>>>(x, w, out, ws);
        vq_loss_fin_fb<<<1, 1, 0, stream>>>(ws, out);
    }
}

// Round 18
// 135.299 us; speedup vs baseline: 1.0249x; 1.0249x over previous
//
#include <hip/hip_runtime.h>
#include <hip/hip_bf16.h>

// Output layout (ALL float32):
//   out[0        .. 8388608)  quantized_st  [4,64,32,32,32]
//   out[8388608  .. 8519680)  embed_idx as float  [4,32,32,32]
//   out[8519680]              latent_loss scalar
#define HWD      32768
#define NC       64
#define NE       512
#define OUT_IDX  8388608
#define OUT_LOSS 8519680

// ws layout (bytes):
//   [0..4)   loss accumulator (fallback only)   [4..8) counter (unused)
//   [64..2112)   wsq[512]
//   [2112..3136) 256 loss partial slots (R14)
//   [4096..200704) wp 3-plane bf16 codebook (R17 16-code-tile swizzle)
#define WS_WSQ_F   16
#define WS_SLOT_F  528
#define WS_WP_B    4096
#define WS_NEEDED  200704

typedef __attribute__((ext_vector_type(8))) short bf16x8;
typedef __attribute__((ext_vector_type(4))) float f32x4;

__device__ inline unsigned short bf16_rne(float v) {
    unsigned u = __builtin_bit_cast(unsigned, v);
    return (unsigned short)((u + 0x7FFFu + ((u >> 16) & 1u)) >> 16);
}
__device__ inline float bf16_f(unsigned short s) {
    return __builtin_bit_cast(float, (unsigned)s << 16);
}
__device__ inline void split3(float v, unsigned short& h, unsigned short& m,
                              unsigned short& l) {
    h = bf16_rne(v);
    float r1 = v - bf16_f(h);
    m = bf16_rne(r1);
    float r2 = r1 - bf16_f(m);
    l = bf16_rne(r2);
}

// ---------------- prep: zero accumulators, wsq, split+swizzle codebook ----
__global__ __launch_bounds__(256) void vq_prep(
    const float* __restrict__ w, float* __restrict__ ws)
{
    const int gtid = blockIdx.x * 256 + threadIdx.x;   // 0..12287
    if (gtid == 0) { ws[0] = 0.f; ((unsigned*)ws)[1] = 0u; }
    if (gtid < 256) ws[WS_SLOT_F + gtid] = 0.f;        // R14 loss slots
    if (gtid < NE) {
        const float4* row = (const float4*)(w + (size_t)gtid * NC);
        float s0 = 0.f, s1 = 0.f, s2 = 0.f, s3 = 0.f;
#pragma unroll
        for (int k = 0; k < 16; ++k) {
            float4 v = row[k];
            s0 = fmaf(v.x, v.x, s0); s1 = fmaf(v.y, v.y, s1);
            s2 = fmaf(v.z, v.z, s2); s3 = fmaf(v.w, v.w, s3);
        }
        ws[WS_WSQ_F + gtid] = (s0 + s1) + (s2 + s3);
    }
    const int lane_s = gtid & 63;
    int t = gtid >> 6;            // 0..191
    const int plane = t % 3; t /= 3;
    const int kc = t & 1;
    const int ct = t >> 1;
    const int code = ct * 16 + (lane_s & 15);
    const int kb   = kc * 32 + (lane_s >> 4) * 8;
    const float* src = w + (size_t)code * NC + kb;
    unsigned short o[8];
#pragma unroll
    for (int j = 0; j < 8; ++j) {
        unsigned short h, m, l;
        split3(src[j], h, m, l);
        o[j] = (plane == 0) ? h : (plane == 1) ? m : l;
    }
    unsigned short* dst = (unsigned short*)((char*)ws + WS_WP_B) + (size_t)gtid * 8;
#pragma unroll
    for (int j = 0; j < 8; ++j) dst[j] = o[j];
}

// ---- R17 helpers ---------------------------------------------------------
// per-wave register B-tile load (6 bf16x8 from L2-resident codebook + wsq)
__device__ __forceinline__ void loadB(const bf16x8* __restrict__ wp,
                                      const float* __restrict__ wsqp,
                                      const int ct, const int lane,
                                      const int lanelo,
                                      bf16x8 (&B)[2][3], float& wsq)
{
#pragma unroll
    for (int kc = 0; kc < 2; ++kc)
#pragma unroll
        for (int p = 0; p < 3; ++p)
            B[kc][p] = wp[(size_t)((ct * 2 + kc) * 3 + p) * 64 + lane];
    wsq = wsqp[ct * 16 + lanelo];
}

// NOTE R11 (verified): xsq dropped — uniform over codes, argmin unchanged.
// R17: the 4 position-subtiles' MFMA chains are INTERLEAVED (step-major) so
// every MFMA's dependency is 4 instructions back, not 1. Per-acc product
// order identical to R7..R16 — bit-identical numerics.
__device__ __forceinline__ void tileUpd4(const bf16x8 (&A)[4][2][3],
                                         const bf16x8 (&B)[2][3],
                                         const float wsq, const int ct,
                                         const int lanelo,
                                         float (&best)[4][4], int (&bidx)[4][4])
{
    // step s -> (kc = s&1, a_plane = AP[s>>1], b_plane = BP[s>>1])
    constexpr int AP[6] = {2, 1, 0, 1, 0, 0};
    constexpr int BP[6] = {0, 1, 2, 0, 1, 0};
    f32x4 acc[4];
#pragma unroll
    for (int pt = 0; pt < 4; ++pt) acc[pt] = (f32x4){0.f, 0.f, 0.f, 0.f};
#pragma unroll
    for (int s = 0; s < 12; ++s) {
        const int kc = s & 1, ap = AP[s >> 1], bp = BP[s >> 1];
#pragma unroll
        for (int pt = 0; pt < 4; ++pt)
            acc[pt] = __builtin_amdgcn_mfma_f32_16x16x32_bf16(
                A[pt][kc][ap], B[kc][bp], acc[pt], 0, 0, 0);
    }
#pragma unroll
    for (int pt = 0; pt < 4; ++pt)
#pragma unroll
        for (int r = 0; r < 4; ++r) {
            const float d = fmaf(-2.f, acc[pt][r], wsq);
            if (d < best[pt][r]) { best[pt][r] = d; bidx[pt][r] = ct * 16 + lanelo; }
        }
}

// ---------------- kernel A: argmin (R17 — final, session best) ------------
// FINAL. 52 us, MfmaUtil ~37%, VGPR 112, no spill. Eight structural
// variants bracket this (R12-R24): LDS-staged barriered/drifted/fat-wave,
// VALU-pipelined (128-cap spill), 32x32 shape (2x codebook traffic),
// setprio (null), TLP x2 via small blocks (64-clamp spill) and via
// grid-doubling (occupancy flat, per-wave overhead up, -12%). The ~37%
// MfmaUtil plateau is the 2-phase-class structural ceiling; past it lies
// the 8-phase counted-vmcnt rewrite. B in registers per wave, ping-pong
// prefetched from the L2-resident codebook; zero barriers in the main loop.
__global__ __launch_bounds__(256, 2) void vq_argmin(
    const float* __restrict__ x, float* __restrict__ ws,
    float* __restrict__ out)
{
    __shared__ int idx_sh[256];

    const int tid    = threadIdx.x;
    const int wv     = tid >> 6;
    const int lane   = tid & 63;
    const int lanelo = lane & 15;
    const int quad   = lane >> 4;
    const int posB   = blockIdx.x * 256;
    const int b      = posB >> 15;
    const int hwdB   = posB & (HWD - 1);
    const size_t xoff = (size_t)b * NC * HWD + hwdB;
    const int wpos   = wv * 64;                  // 64 positions per wave

    const bf16x8* wp   = (const bf16x8*)((const char*)ws + WS_WP_B);
    const float*  wsqp = ws + WS_WSQ_F;

    // issue tile-0 B load NOW so L2 latency rides under the x prologue
    bf16x8 B0[2][3], B1[2][3];
    float  w0, w1;
    loadB(wp, wsqp, 0, lane, lanelo, B0, w0);

    // ---- phase 1: A-fragments, 4 position-subtiles (3 exact bf16 planes) -
    bf16x8 A[4][2][3];
#pragma unroll
    for (int pt = 0; pt < 4; ++pt) {
#pragma unroll
        for (int kc = 0; kc < 2; ++kc) {
            bf16x8 fh, fm, fl;
#pragma unroll
            for (int j = 0; j < 8; ++j) {
                const int k = kc * 32 + quad * 8 + j;
                const float v = x[xoff + (size_t)k * HWD + wpos + pt * 16 + lanelo];
                unsigned short h, m, l;
                split3(v, h, m, l);
                fh[j] = (short)h; fm[j] = (short)m; fl[j] = (short)l;
            }
            A[pt][kc][0] = fh; A[pt][kc][1] = fm; A[pt][kc][2] = fl;
        }
    }

    float best[4][4];
    int   bidx[4][4];
#pragma unroll
    for (int pt = 0; pt < 4; ++pt)
#pragma unroll
        for (int r = 0; r < 4; ++r) { best[pt][r] = 3.402823466e38f; bidx[pt][r] = 0; }

    // ---- phase 2: 32 tiles, ping-pong reg prefetch, NO barriers ----------
#pragma unroll 1
    for (int r = 0; r < 16; ++r) {
        const int ce = r * 2;
        loadB(wp, wsqp, ce + 1, lane, lanelo, B1, w1);          // prefetch odd
        tileUpd4(A, B0, w0, ce, lanelo, best, bidx);            // compute even
        loadB(wp, wsqp, (ce + 2) & 31, lane, lanelo, B0, w0);   // prefetch next
        tileUpd4(A, B1, w1, ce + 1, lanelo, best, bidx);        // compute odd
    }

    // ---- phase 3: argmin across 16 code-columns (np first-index ties) ----
#pragma unroll
    for (int pt = 0; pt < 4; ++pt)
#pragma unroll
        for (int r = 0; r < 4; ++r) {
            float d = best[pt][r]; int i = bidx[pt][r];
#pragma unroll
            for (int mlane = 1; mlane <= 8; mlane <<= 1) {
                const float d2 = __shfl_xor(d, mlane);
                const int   i2 = __shfl_xor(i, mlane);
                if (d2 < d || (d2 == d && i2 < i)) { d = d2; i = i2; }
            }
            if (lanelo == 0)
                idx_sh[wpos + pt * 16 + quad * 4 + r] = i;
        }
    __syncthreads();

    out[OUT_IDX + posB + tid] = (float)idx_sh[tid];
}

// ---------------- kernel B: streaming epilogue (R15 float4, verified) -----
__global__ __launch_bounds__(256, 8) void vq_epilogue(
    const float* __restrict__ x, const float* __restrict__ w,
    float* __restrict__ ws, float* __restrict__ out)
{
    __shared__ float q_t[64 * 68];     // 17.4 KB, [channel][pos], pad 68
    __shared__ int   idx_sh[64];
    __shared__ float wred[4];

    const int tid  = threadIdx.x;
    const int posB = blockIdx.x * 64;
    const int b    = posB >> 15;
    const int hwdB = posB & (HWD - 1);
    const size_t xoff = (size_t)b * NC * HWD + hwdB;

    if (tid < 64) idx_sh[tid] = (int)out[OUT_IDX + posB + tid];
    __syncthreads();

#pragma unroll
    for (int it = 0; it < 16; ++it) {
        const int e = it * 256 + tid;
        const int r = e >> 6, c = e & 63;
        q_t[c * 68 + r] = w[(size_t)idx_sh[r] * NC + c];
    }
    __syncthreads();

    float lsum = 0.f;
#pragma unroll
    for (int it = 0; it < 4; ++it) {
        const int s  = it * 256 + tid;
        const int c  = s >> 4;             // 0..63
        const int p0 = (s & 15) * 4;       // 0,4,..,60
        const size_t off = xoff + (size_t)c * HWD + p0;
        const float4 xv = *(const float4*)(x + off);
        const float4 qv = *(const float4*)(q_t + c * 68 + p0);
        const float dx = qv.x - xv.x, dy = qv.y - xv.y;
        const float dz = qv.z - xv.z, dw = qv.w - xv.w;
        lsum = fmaf(dx, dx, lsum); lsum = fmaf(dy, dy, lsum);
        lsum = fmaf(dz, dz, lsum); lsum = fmaf(dw, dw, lsum);
        float4 ov;
        ov.x = dx + xv.x; ov.y = dy + xv.y;
        ov.z = dz + xv.z; ov.w = dw + xv.w;
        *(float4*)(out + off) = ov;
    }

#pragma unroll
    for (int off = 32; off >= 1; off >>= 1) lsum += __shfl_down(lsum, off);
    if ((tid & 63) == 0) wred[tid >> 6] = lsum;
    __syncthreads();
    if (tid == 0)
        atomicAdd(ws + WS_SLOT_F + (blockIdx.x & 255),
                  (wred[0] + wred[1]) + (wred[2] + wred[3]));
}

// ---------------- kernel C: reduce the 256 loss slots ---------------------
__global__ __launch_bounds__(64) void vq_loss_fin(
    const float* __restrict__ ws, float* __restrict__ out)
{
    const int lane = threadIdx.x;
    float s = (ws[WS_SLOT_F + lane]       + ws[WS_SLOT_F + lane + 64]) +
              (ws[WS_SLOT_F + lane + 128] + ws[WS_SLOT_F + lane + 192]);
#pragma unroll
    for (int off = 32; off >= 1; off >>= 1) s += __shfl_down(s, off);
    if (lane == 0) out[OUT_LOSS] = 0.25f * s / 8388608.0f;
}

// ---------------- fallback (R4 structure, known-passing) ------------------
__global__ __launch_bounds__(256, 2) void vq_fused_fb(
    const float* __restrict__ x, const float* __restrict__ w,
    float* __restrict__ out, float* __restrict__ loss_acc)
{
    __shared__ float lw[256 * NC];
    __shared__ float wsq[256];
    __shared__ float wred[4];
    const int tid = threadIdx.x;
    const int n0  = blockIdx.x * 512;
    const int b   = n0 >> 15;
    const int hwd = (n0 & (HWD - 1)) + tid;
    const float* xp = x + (size_t)b * NC * HWD + hwd;
    float xr0[NC], xr1[NC];
#pragma unroll
    for (int c = 0; c < NC; ++c) { xr0[c] = xp[(size_t)c * HWD]; xr1[c] = xp[(size_t)c * HWD + 256]; }
    float xsq0 = 0.f, xsq1 = 0.f;
#pragma unroll
    for (int c = 0; c < NC; ++c) { xsq0 = fmaf(xr0[c], xr0[c], xsq0); xsq1 = fmaf(xr1[c], xr1[c], xsq1); }
    float best0 = 3.402823466e38f, best1 = 3.402823466e38f;
    int bi0 = 0, bi1 = 0;
    for (int pass = 0; pass < 2; ++pass) {
        if (pass) __syncthreads();
        const float4* wt = (const float4*)(w + pass * 256 * NC);
        float4* l4 = (float4*)lw;
#pragma unroll
        for (int k = 0; k < 16; ++k) l4[tid + k * 256] = wt[tid + k * 256];
        {
            const float4* row = wt + tid * 16;
            float s0 = 0.f, s1 = 0.f, s2 = 0.f, s3 = 0.f;
#pragma unroll
            for (int k = 0; k < 16; ++k) {
                float4 v = row[k];
                s0 = fmaf(v.x, v.x, s0); s1 = fmaf(v.y, v.y, s1);
                s2 = fmaf(v.z, v.z, s2); s3 = fmaf(v.w, v.w, s3);
            }
            wsq[tid] = (s0 + s1) + (s2 + s3);
        }
        __syncthreads();
#pragma unroll 2
        for (int e = 0; e < 256; ++e) {
            const float4* row = (const float4*)(lw + e * NC);
            float a0 = 0.f, a1 = 0.f, c0 = 0.f, c1 = 0.f;
#pragma unroll
            for (int k = 0; k < 16; ++k) {
                float4 v = row[k];
                a0 = fmaf(xr0[4 * k + 0], v.x, a0); a1 = fmaf(xr0[4 * k + 1], v.y, a1);
                a0 = fmaf(xr0[4 * k + 2], v.z, a0); a1 = fmaf(xr0[4 * k + 3], v.w, a1);
                c0 = fmaf(xr1[4 * k + 0], v.x, c0); c1 = fmaf(xr1[4 * k + 1], v.y, c1);
                c0 = fmaf(xr1[4 * k + 2], v.z, c0); c1 = fmaf(xr1[4 * k + 3], v.w, c1);
            }
            const float d0 = (xsq0 - 2.f * (a0 + a1)) + wsq[e];
            const float d1 = (xsq1 - 2.f * (c0 + c1)) + wsq[e];
            const int ge = pass * 256 + e;
            if (d0 < best0) { best0 = d0; bi0 = ge; }
            if (d1 < best1) { best1 = d1; bi1 = ge; }
        }
    }
    float* o0 = out + (size_t)b * NC * HWD + hwd;
    float lsum = 0.f;
    const float4* r0 = (const float4*)(w + bi0 * NC);
    const float4* r1 = (const float4*)(w + bi1 * NC);
#pragma unroll
    for (int k = 0; k < 16; ++k) {
        float4 q0 = r0[k], q1 = r1[k];
        float qv0[4] = { q0.x, q0.y, q0.z, q0.w };
        float qv1[4] = { q1.x, q1.y, q1.z, q1.w };
#pragma unroll
        for (int j = 0; j < 4; ++j) {
            const int c = 4 * k + j;
            const float dv0 = qv0[j] - xr0[c];
            const float dv1 = qv1[j] - xr1[c];
            lsum = fmaf(dv0, dv0, lsum); lsum = fmaf(dv1, dv1, lsum);
            o0[(size_t)c * HWD] = dv0 + xr0[c];
            o0[(size_t)c * HWD + 256] = dv1 + xr1[c];
        }
    }
    const int n = b * HWD + hwd;
    out[OUT_IDX + n] = (float)bi0;
    out[OUT_IDX + n + 256] = (float)bi1;
#pragma unroll
    for (int off = 32; off >= 1; off >>= 1) lsum += __shfl_down(lsum, off);
    if ((tid & 63) == 0) wred[tid >> 6] = lsum;
    __syncthreads();
    if (tid == 0) atomicAdd(loss_acc, (wred[0] + wred[1]) + (wred[2] + wred[3]));
}

__global__ void vq_loss_fin_fb(const float* __restrict__ acc, float* __restrict__ out)
{
    out[OUT_LOSS] = 0.25f * acc[0] / 8388608.0f;
}

extern "C" void kernel_launch(void* const* d_in, const int* in_sizes, int n_in,
                              void* d_out, int out_size, void* d_ws, size_t ws_size,
                              hipStream_t stream)
{
    const float* x = (const float*)d_in[0];
    const float* w = (const float*)d_in[1];
    float* out = (float*)d_out;
    float* ws  = (float*)d_ws;

    if (ws_size >= WS_NEEDED) {
        vq_prep<<<48, 256, 0, stream>>>(w, ws);
        vq_argmin<<<512, 256, 0, stream>>>(x, ws, out);
        vq_epilogue<<<2048, 256, 0, stream>>>(x, w, ws, out);
        vq_loss_fin<<<1, 64, 0, stream>>>(ws, out);
    } else {
        hipMemsetAsync(d_ws, 0, sizeof(float), stream);
        vq_fused_fb<<<256, 256, 0, stream>>>(x, w, out, ws);
        vq_loss_fin_fb<<<1, 1, 0, stream>>>(ws, out);
    }
}